// Round 1
// baseline (283.714 us; speedup 1.0000x reference)
//
#include <hip/hip_runtime.h>

#define BB 32
#define LL 2048
#define DD 768

// ---------------------------------------------------------------------------
// Kernel A: per-token weights + per-row norm (atomic partial sums).
// grid = (L/256, B), block = 256.
// Each block stages the FULL row of masked ids in LDS (8 KB), computes
// n_valid by block-reduce, then each thread computes its token's count by
// scanning the row with int4 broadcast LDS reads (conflict-free broadcast).
// ---------------------------------------------------------------------------
__global__ __launch_bounds__(256) void weights_kernel(
    const int* __restrict__ ids, const int* __restrict__ mask,
    const float* __restrict__ idf, const float* __restrict__ alpha_p,
    float* __restrict__ w_ws, float* __restrict__ norm_ws)
{
    __shared__ int   ids_s[LL];
    __shared__ int   ired[4];
    __shared__ float fred[4];
    __shared__ int   nvalid_s;

    const int tid = threadIdx.x;
    const int b   = blockIdx.y;
    const int seg = blockIdx.x;

    const int* ids_row  = ids  + b * LL;
    const int* mask_row = mask + b * LL;

    // Stage masked ids (invalid -> -1 so they never match a real id), count valid.
    int local_valid = 0;
    for (int j = tid; j < LL; j += 256) {
        int m  = mask_row[j];
        int id = ids_row[j];
        ids_s[j] = m ? id : -1;
        local_valid += m;
    }
    // n_valid = block reduction
    #pragma unroll
    for (int off = 32; off; off >>= 1) local_valid += __shfl_down(local_valid, off, 64);
    const int wave = tid >> 6;
    if ((tid & 63) == 0) ired[wave] = local_valid;
    __syncthreads();
    if (tid == 0) nvalid_s = ired[0] + ired[1] + ired[2] + ired[3];
    __syncthreads();

    // Count occurrences of my token's id among VALID positions of the row.
    const int l     = seg * 256 + tid;
    const int my_id = ids_row[l];
    int cnt = 0;
    const int4* ids4 = (const int4*)ids_s;
    #pragma unroll 8
    for (int j4 = 0; j4 < LL / 4; ++j4) {
        int4 v = ids4[j4];
        cnt += (v.x == my_id) + (v.y == my_id) + (v.z == my_id) + (v.w == my_id);
    }

    const float m  = (float)mask_row[l];
    const float nv = fmaxf((float)nvalid_s, 1.0f);
    const float tf = (float)cnt / nv;
    const float w  = (1.0f + alpha_p[0] * tf * idf[my_id]) * m;
    w_ws[b * LL + l] = w;

    // Partial row-sum of weights -> atomic into norm_ws[b]
    float wsum = w;
    #pragma unroll
    for (int off = 32; off; off >>= 1) wsum += __shfl_down(wsum, off, 64);
    if ((tid & 63) == 0) fred[wave] = wsum;
    __syncthreads();
    if (tid == 0) atomicAdd(&norm_ws[b], fred[0] + fred[1] + fred[2] + fred[3]);
}

// ---------------------------------------------------------------------------
// Kernel C: weighted pooling. grid = (32 segments, B), block = 192 (= D/4).
// Each block handles 64 tokens of one row; lane t owns float4 d-slot t.
// Zero-weight tokens (mask==0, ~50%) are skipped entirely -> halves HBM read.
// Branch is wave-uniform (w broadcast from LDS). Partials atomicAdd into the
// pre-zeroed output with 1/norm folded in.
// ---------------------------------------------------------------------------
__global__ __launch_bounds__(192) void pool_kernel(
    const float* __restrict__ h, const float* __restrict__ w_ws,
    const float* __restrict__ norm_ws, float* __restrict__ out)
{
    const int tid = threadIdx.x;
    const int b   = blockIdx.y;
    const int seg = blockIdx.x;
    const int l0  = seg * 64;

    __shared__ float w_s[64];
    __shared__ float inv_s;
    if (tid < 64) w_s[tid] = w_ws[b * LL + l0 + tid];
    if (tid == 0) inv_s = 1.0f / fmaxf(norm_ws[b], 1e-12f);
    __syncthreads();

    const float4* h4 = (const float4*)(h + ((size_t)b * LL + l0) * DD);
    float4 acc = make_float4(0.f, 0.f, 0.f, 0.f);
    #pragma unroll 4
    for (int i = 0; i < 64; ++i) {
        const float w = w_s[i];
        if (w != 0.0f) {                      // wave-uniform skip
            float4 v = h4[i * (DD / 4) + tid];
            acc.x = fmaf(v.x, w, acc.x);
            acc.y = fmaf(v.y, w, acc.y);
            acc.z = fmaf(v.z, w, acc.z);
            acc.w = fmaf(v.w, w, acc.w);
        }
    }
    const float inv = inv_s;
    float* o = out + b * DD + tid * 4;
    atomicAdd(o + 0, acc.x * inv);
    atomicAdd(o + 1, acc.y * inv);
    atomicAdd(o + 2, acc.z * inv);
    atomicAdd(o + 3, acc.w * inv);
}

extern "C" void kernel_launch(void* const* d_in, const int* in_sizes, int n_in,
                              void* d_out, int out_size, void* d_ws, size_t ws_size,
                              hipStream_t stream)
{
    const float* h     = (const float*)d_in[0];   // [B,L,D] fp32
    const int*   mask  = (const int*)  d_in[1];   // [B,L] int
    const int*   ids   = (const int*)  d_in[2];   // [B,L] int (harness narrows ints)
    const float* idf   = (const float*)d_in[3];   // [V] fp32
    const float* alpha = (const float*)d_in[4];   // scalar
    float*       out   = (float*)d_out;           // [B,D] fp32

    float* w_ws    = (float*)d_ws;                // B*L floats = 256 KB
    float* norm_ws = w_ws + BB * LL;              // B floats

    hipMemsetAsync(d_out, 0, (size_t)out_size * sizeof(float), stream);
    hipMemsetAsync(norm_ws, 0, BB * sizeof(float), stream);

    weights_kernel<<<dim3(LL / 256, BB), 256, 0, stream>>>(
        ids, mask, idf, alpha, w_ws, norm_ws);
    pool_kernel<<<dim3(32, BB), 192, 0, stream>>>(
        h, w_ws, norm_ws, out);
}

// Round 2
// 265.205 us; speedup vs baseline: 1.0698x; 1.0698x over previous
//
#include <hip/hip_runtime.h>

#define BB 32
#define LL 2048
#define DD 768
#define VV 32000
#define NSEG 16

// ---------------------------------------------------------------------------
// K1: one block per row (grid=32, block=256). O(L) via LDS histogram:
// 32000 16-bit counters packed 2-per-u32 (64000 B < 64 KB static limit).
// Each thread owns 8 contiguous tokens (int4 x2 loads). Computes per-token
// weight, compacts valid (w,l) pairs via block scan, and the row norm —
// all within one block, so no global atomics and fully deterministic.
// ---------------------------------------------------------------------------
__global__ __launch_bounds__(256) void weights_kernel(
    const int* __restrict__ ids, const int* __restrict__ mask,
    const float* __restrict__ idf, const float* __restrict__ alpha_p,
    float* __restrict__ wc, int* __restrict__ lc,
    int* __restrict__ nv_ws, float* __restrict__ inv_ws)
{
    __shared__ unsigned int hist[VV / 2];   // 64000 B, packed 2x16-bit counts
    __shared__ int scan_s[256];

    const int tid = threadIdx.x;
    const int b   = blockIdx.x;

    for (int i = tid; i < VV / 2; i += 256) hist[i] = 0u;

    const int4* ids4 = (const int4*)(ids  + b * LL);
    const int4* msk4 = (const int4*)(mask + b * LL);
    const int4 ia = ids4[2 * tid], ib = ids4[2 * tid + 1];
    const int4 ma = msk4[2 * tid], mb = msk4[2 * tid + 1];
    const int idv[8] = {ia.x, ia.y, ia.z, ia.w, ib.x, ib.y, ib.z, ib.w};
    const int mv[8]  = {ma.x, ma.y, ma.z, ma.w, mb.x, mb.y, mb.z, mb.w};

    __syncthreads();                        // hist zeroed

    int c_t = 0;
    #pragma unroll
    for (int k = 0; k < 8; ++k) {
        if (mv[k]) {
            atomicAdd(&hist[idv[k] >> 1], 1u << ((idv[k] & 1) * 16));
            c_t++;
        }
    }

    // Block inclusive scan over per-thread valid counts (barrier also orders
    // the histogram atomics before the reads below).
    scan_s[tid] = c_t;
    __syncthreads();
    for (int off = 1; off < 256; off <<= 1) {
        const int v   = scan_s[tid];
        const int add = (tid >= off) ? scan_s[tid - off] : 0;
        __syncthreads();
        scan_s[tid] = v + add;
        __syncthreads();
    }
    const int excl        = scan_s[tid] - c_t;
    const int total_valid = scan_s[255];
    __syncthreads();                        // scan reads done before reuse

    const float nvf   = fmaxf((float)total_valid, 1.0f);
    const float alpha = alpha_p[0];

    float wsum = 0.0f;
    float wv[8];
    #pragma unroll
    for (int k = 0; k < 8; ++k) {
        const int id        = idv[k];
        const unsigned raw  = hist[id >> 1];
        const int cnt       = (raw >> ((id & 1) * 16)) & 0xffff;
        const float tf      = (float)cnt / nvf;
        const float w       = (1.0f + alpha * tf * idf[id]) * (float)(mv[k] != 0);
        wv[k] = w;
        wsum += w;
    }

    int pos = b * LL + excl;
    #pragma unroll
    for (int k = 0; k < 8; ++k) {
        if (mv[k]) { wc[pos] = wv[k]; lc[pos] = tid * 8 + k; pos++; }
    }

    // Row norm: shuffle-reduce + LDS (reuse scan_s as float bits).
    #pragma unroll
    for (int off = 32; off; off >>= 1) wsum += __shfl_down(wsum, off, 64);
    if ((tid & 63) == 0) scan_s[tid >> 6] = __float_as_int(wsum);
    __syncthreads();
    if (tid == 0) {
        const float t = __int_as_float(scan_s[0]) + __int_as_float(scan_s[1])
                      + __int_as_float(scan_s[2]) + __int_as_float(scan_s[3]);
        inv_ws[b] = 1.0f / fmaxf(t, 1e-12f);
        nv_ws[b]  = total_valid;
    }
}

// ---------------------------------------------------------------------------
// K2: pooling over the COMPACTED token list — branch-free inner loop, each
// wave owns all of D (lane = 3x float4), 3 independent 1KB-coalesced loads
// per token so the compiler can keep many loads in flight.
// grid = (NSEG, B), block = 256 (4 waves). Wave ww = seg*4+wave handles
// compacted tokens j = ww, ww+64, ... Partials to ws (no atomics/memset).
// ---------------------------------------------------------------------------
__global__ __launch_bounds__(256) void pool_kernel(
    const float* __restrict__ h, const float* __restrict__ wc,
    const int* __restrict__ lc, const int* __restrict__ nv_ws,
    float* __restrict__ part)
{
    __shared__ float red[4 * DD];           // 12 KB
    const int tid  = threadIdx.x;
    const int wave = tid >> 6, lane = tid & 63;
    const int b = blockIdx.y, s = blockIdx.x;
    const int nv = nv_ws[b];
    const int ww = s * 4 + wave;            // 0..63

    const float* hb = h + (size_t)b * (LL * DD);
    float4 a0 = {0, 0, 0, 0}, a1 = {0, 0, 0, 0}, a2 = {0, 0, 0, 0};
    for (int j = ww; j < nv; j += 64) {
        const float w = wc[b * LL + j];
        const int   l = lc[b * LL + j];
        const float4* hp = (const float4*)(hb + (size_t)l * DD);
        const float4 v0 = hp[lane];
        const float4 v1 = hp[64 + lane];
        const float4 v2 = hp[128 + lane];
        a0.x = fmaf(v0.x, w, a0.x); a0.y = fmaf(v0.y, w, a0.y);
        a0.z = fmaf(v0.z, w, a0.z); a0.w = fmaf(v0.w, w, a0.w);
        a1.x = fmaf(v1.x, w, a1.x); a1.y = fmaf(v1.y, w, a1.y);
        a1.z = fmaf(v1.z, w, a1.z); a1.w = fmaf(v1.w, w, a1.w);
        a2.x = fmaf(v2.x, w, a2.x); a2.y = fmaf(v2.y, w, a2.y);
        a2.z = fmaf(v2.z, w, a2.z); a2.w = fmaf(v2.w, w, a2.w);
    }

    float4* r = (float4*)(red + wave * DD);
    r[lane] = a0; r[64 + lane] = a1; r[128 + lane] = a2;
    __syncthreads();
    for (int k = tid; k < DD; k += 256) {
        part[((size_t)b * NSEG + s) * DD + k] =
            red[k] + red[DD + k] + red[2 * DD + k] + red[3 * DD + k];
    }
}

// ---------------------------------------------------------------------------
// K3: sum NSEG partials per (b,d), scale by 1/norm. grid = 96, block = 256.
// ---------------------------------------------------------------------------
__global__ __launch_bounds__(256) void finalize_kernel(
    const float* __restrict__ part, const float* __restrict__ inv_ws,
    float* __restrict__ out)
{
    const int idx = blockIdx.x * 256 + threadIdx.x;   // 0..24575
    const int b = idx / DD, d = idx - b * DD;
    float s = 0.0f;
    #pragma unroll
    for (int k = 0; k < NSEG; ++k) s += part[((size_t)b * NSEG + k) * DD + d];
    out[idx] = s * inv_ws[b];
}

extern "C" void kernel_launch(void* const* d_in, const int* in_sizes, int n_in,
                              void* d_out, int out_size, void* d_ws, size_t ws_size,
                              hipStream_t stream)
{
    const float* h     = (const float*)d_in[0];   // [B,L,D] fp32
    const int*   mask  = (const int*)  d_in[1];   // [B,L]
    const int*   ids   = (const int*)  d_in[2];   // [B,L]
    const float* idf   = (const float*)d_in[3];   // [V]
    const float* alpha = (const float*)d_in[4];   // scalar
    float*       out   = (float*)d_out;           // [B,D]

    float* wc   = (float*)d_ws;                   // B*L floats
    int*   lc   = (int*)(wc + BB * LL);           // B*L ints
    int*   nv   = lc + BB * LL;                   // B ints
    float* inv  = (float*)(nv + BB);              // B floats
    float* part = inv + BB;                       // B*NSEG*D floats (1.5 MB)

    weights_kernel<<<BB, 256, 0, stream>>>(ids, mask, idf, alpha, wc, lc, nv, inv);
    pool_kernel<<<dim3(NSEG, BB), 256, 0, stream>>>(h, wc, lc, nv, part);
    finalize_kernel<<<(BB * DD) / 256, 256, 0, stream>>>(part, inv, out);
}